// Round 14
// baseline (178.479 us; speedup 1.0000x reference)
//
#include <hip/hip_runtime.h>

#define N_NODES 20000
#define D_FEAT 256
#define N_SUPPORT 3
#define N_EDGES 320000
#define OUT_DIM 256
#define TOTAL_E (N_SUPPORT * N_EDGES)
#define CAP 64                      // per-(s,dst) bucket; mean 16, P(>64) ~ 1e-9
#define KDIM (N_SUPPORT * D_FEAT)   // 768
#define HPAD (KDIM + 8)             // 776 shorts; rows 16B-aligned
#define TILE 16

typedef __attribute__((ext_vector_type(8))) short short8;
typedef __attribute__((ext_vector_type(8))) unsigned short ushort8;
typedef __attribute__((ext_vector_type(4))) float f32x4;

__device__ inline unsigned short f2bf(float f) {
    unsigned int u = __float_as_uint(f);
    u += 0x7fff + ((u >> 16) & 1);  // round-to-nearest-even
    return (unsigned short)(u >> 16);
}
__device__ inline float bfhi(unsigned int p) {      // bf16 in high 16 bits -> float
    return __uint_as_float(p & 0xFFFF0000u);
}

// ---------------- prep: quantize_x | convert_w | fill_edges (one launch, no cross-range deps) ----------------
#define NB_X (N_NODES / 4)          // 5000 blocks, 4 waves/block, 1 row/wave
#define NB_W (N_SUPPORT * D_FEAT)   // 768
#define NB_F (TOTAL_E / 256)        // 3750

__global__ void __launch_bounds__(256) prep(const float* __restrict__ x, const float* __restrict__ W,
        const int* __restrict__ src, const int* __restrict__ dst, const float* __restrict__ w,
        unsigned int* __restrict__ xq, float* __restrict__ scl, unsigned short* __restrict__ wt,
        int* __restrict__ cursor, unsigned int* __restrict__ epack) {
    const int bid = blockIdx.x;
    const int tid = threadIdx.x;
    if (bid < NB_X) {
        // per-row int8 quantization: row = bid*4 + wid, lane owns 4 cols
        const int row = bid * 4 + (tid >> 6);
        const int lane = tid & 63;
        float4 v = ((const float4*)x)[row * 64 + lane];
        float m = fmaxf(fmaxf(fabsf(v.x), fabsf(v.y)), fmaxf(fabsf(v.z), fabsf(v.w)));
#pragma unroll
        for (int d = 1; d < 64; d <<= 1) m = fmaxf(m, __shfl_xor(m, d, 64));
        const float inv = (m > 0.f) ? 127.0f / m : 0.f;
        int q0 = (int)rintf(v.x * inv) + 128;
        int q1 = (int)rintf(v.y * inv) + 128;
        int q2 = (int)rintf(v.z * inv) + 128;
        int q3 = (int)rintf(v.w * inv) + 128;
        unsigned int pk = (unsigned int)q0 | ((unsigned int)q1 << 8)
                        | ((unsigned int)q2 << 16) | ((unsigned int)q3 << 24);
        xq[row * 64 + lane] = pk;
        if (lane == 0) scl[row] = m * (1.0f / 127.0f);
    } else if (bid < NB_X + NB_W) {
        const int row = bid - NB_X;        // s*256 + k
        const int s = row >> 8, k = row & 255;
        wt[((size_t)s * OUT_DIM + tid) * D_FEAT + k] = f2bf(W[(size_t)row * OUT_DIM + tid]);
    } else {
        // fill: store RAW bf16 weight; dequant scale applied at gather time
        const int i = (bid - NB_X - NB_W) * 256 + tid;
        const int s = i / N_EDGES;
        const int sv = src[i];
        const int b = s * N_NODES + dst[i];
        const int pos = atomicAdd(&cursor[b], 1);
        if (pos < CAP)
            epack[(size_t)b * CAP + pos] = (unsigned int)sv | (((unsigned int)f2bf(w[i])) << 16);
    }
}

// ---------------- fused: int8 gather (ILP-8) -> h (LDS) -> h @ W via MFMA ----------------
__global__ void __launch_bounds__(512) fused_gather_gemm(
        const unsigned char* __restrict__ xq, const float* __restrict__ scl,
        const unsigned short* __restrict__ wt,
        const int* __restrict__ cursor, const unsigned int* __restrict__ epack,
        float* __restrict__ out) {
    __shared__ unsigned short h[TILE][HPAD];   // 24,832 B
    const int n0 = blockIdx.x * TILE;
    const int wid = threadIdx.x >> 6;
    const int lane = threadIdx.x & 63;
    const int half = lane >> 5;
    const int l32 = lane & 31;
    const int xoff = l32 * 8;                  // 8 cols x 1 B

    // ---- phase 1: half -> one node, 3 supports serial, 8 edges in flight ----
    const int lr = wid * 2 + half;
    const int node = n0 + lr;
#pragma unroll
    for (int s = 0; s < N_SUPPORT; ++s) {
        const int b = s * N_NODES + node;
        int cnt = cursor[b]; if (cnt > CAP) cnt = CAP;
        const unsigned int* ep = epack + (size_t)b * CAP;

        float a[8];
#pragma unroll
        for (int j = 0; j < 8; ++j) a[j] = 0.f;
        float sw = 0.f;

        int it = 0;
        for (; it + 7 < cnt; it += 8) {        // 8 independent table loads in flight
            const uint4 pa = *(const uint4*)(ep + it);
            const uint4 pb = *(const uint4*)(ep + it + 4);
            const unsigned int s0 = pa.x & 0xFFFFu, s1 = pa.y & 0xFFFFu;
            const unsigned int s2 = pa.z & 0xFFFFu, s3 = pa.w & 0xFFFFu;
            const unsigned int s4 = pb.x & 0xFFFFu, s5 = pb.y & 0xFFFFu;
            const unsigned int s6 = pb.z & 0xFFFFu, s7 = pb.w & 0xFFFFu;
            const uint2 u0 = *(const uint2*)(xq + ((size_t)s0 << 8) + xoff);
            const uint2 u1 = *(const uint2*)(xq + ((size_t)s1 << 8) + xoff);
            const uint2 u2 = *(const uint2*)(xq + ((size_t)s2 << 8) + xoff);
            const uint2 u3 = *(const uint2*)(xq + ((size_t)s3 << 8) + xoff);
            const uint2 u4 = *(const uint2*)(xq + ((size_t)s4 << 8) + xoff);
            const uint2 u5 = *(const uint2*)(xq + ((size_t)s5 << 8) + xoff);
            const uint2 u6 = *(const uint2*)(xq + ((size_t)s6 << 8) + xoff);
            const uint2 u7 = *(const uint2*)(xq + ((size_t)s7 << 8) + xoff);
            const float w0 = bfhi(pa.x) * scl[s0];
            const float w1 = bfhi(pa.y) * scl[s1];
            const float w2 = bfhi(pa.z) * scl[s2];
            const float w3 = bfhi(pa.w) * scl[s3];
            const float w4 = bfhi(pb.x) * scl[s4];
            const float w5 = bfhi(pb.y) * scl[s5];
            const float w6 = bfhi(pb.z) * scl[s6];
            const float w7 = bfhi(pb.w) * scl[s7];
            sw += (w0 + w1 + w2 + w3) + (w4 + w5 + w6 + w7);
#pragma unroll
            for (int j = 0; j < 4; ++j) {
                const int sh = 8 * j;
                a[j]     += w0 * (float)((u0.x >> sh) & 0xffu) + w1 * (float)((u1.x >> sh) & 0xffu)
                          + w2 * (float)((u2.x >> sh) & 0xffu) + w3 * (float)((u3.x >> sh) & 0xffu)
                          + w4 * (float)((u4.x >> sh) & 0xffu) + w5 * (float)((u5.x >> sh) & 0xffu)
                          + w6 * (float)((u6.x >> sh) & 0xffu) + w7 * (float)((u7.x >> sh) & 0xffu);
                a[4 + j] += w0 * (float)((u0.y >> sh) & 0xffu) + w1 * (float)((u1.y >> sh) & 0xffu)
                          + w2 * (float)((u2.y >> sh) & 0xffu) + w3 * (float)((u3.y >> sh) & 0xffu)
                          + w4 * (float)((u4.y >> sh) & 0xffu) + w5 * (float)((u5.y >> sh) & 0xffu)
                          + w6 * (float)((u6.y >> sh) & 0xffu) + w7 * (float)((u7.y >> sh) & 0xffu);
            }
        }
        if (it + 3 < cnt) {                    // one 4-wide group
            const uint4 pa = *(const uint4*)(ep + it);
            const unsigned int s0 = pa.x & 0xFFFFu, s1 = pa.y & 0xFFFFu;
            const unsigned int s2 = pa.z & 0xFFFFu, s3 = pa.w & 0xFFFFu;
            const uint2 u0 = *(const uint2*)(xq + ((size_t)s0 << 8) + xoff);
            const uint2 u1 = *(const uint2*)(xq + ((size_t)s1 << 8) + xoff);
            const uint2 u2 = *(const uint2*)(xq + ((size_t)s2 << 8) + xoff);
            const uint2 u3 = *(const uint2*)(xq + ((size_t)s3 << 8) + xoff);
            const float w0 = bfhi(pa.x) * scl[s0];
            const float w1 = bfhi(pa.y) * scl[s1];
            const float w2 = bfhi(pa.z) * scl[s2];
            const float w3 = bfhi(pa.w) * scl[s3];
            sw += w0 + w1 + w2 + w3;
#pragma unroll
            for (int j = 0; j < 4; ++j) {
                const int sh = 8 * j;
                a[j]     += w0 * (float)((u0.x >> sh) & 0xffu) + w1 * (float)((u1.x >> sh) & 0xffu)
                          + w2 * (float)((u2.x >> sh) & 0xffu) + w3 * (float)((u3.x >> sh) & 0xffu);
                a[4 + j] += w0 * (float)((u0.y >> sh) & 0xffu) + w1 * (float)((u1.y >> sh) & 0xffu)
                          + w2 * (float)((u2.y >> sh) & 0xffu) + w3 * (float)((u3.y >> sh) & 0xffu);
            }
            it += 4;
        }
        for (; it < cnt; ++it) {               // <=3 scalar cleanup
            const unsigned int pe = ep[it];
            const unsigned int sv = pe & 0xFFFFu;
            const uint2 u = *(const uint2*)(xq + ((size_t)sv << 8) + xoff);
            const float wv = bfhi(pe) * scl[sv];
            sw += wv;
#pragma unroll
            for (int j = 0; j < 4; ++j) {
                const int sh = 8 * j;
                a[j]     += wv * (float)((u.x >> sh) & 0xffu);
                a[4 + j] += wv * (float)((u.y >> sh) & 0xffu);
            }
        }

        ushort8 o;
        const float bias = 128.f * sw;
#pragma unroll
        for (int j = 0; j < 8; ++j) o[j] = f2bf(a[j] - bias);
        *(ushort8*)&h[lr][s * D_FEAT + xoff] = o;
    }
    __syncthreads();

    // ---- phase 2: out_tile[16][256] = h @ W; wave -> 2 n-tiles ----
    const int cit = lane & 15;
    const int kgrp = (lane >> 4) * 8;

    f32x4 acc[2];
#pragma unroll
    for (int j = 0; j < 2; ++j) acc[j] = (f32x4){0.f, 0.f, 0.f, 0.f};

#pragma unroll
    for (int kk = 0; kk < KDIM / 32; ++kk) {   // 24 k-steps
        const int k0 = kk * 32;
        short8 av = *(const short8*)&h[cit][k0 + kgrp];
        const int s = k0 >> 8;
        const int kp = (k0 & 255) + kgrp;
        const short* bbase = (const short*)wt + (size_t)s * D_FEAT * OUT_DIM
                           + (size_t)cit * D_FEAT + kp;
#pragma unroll
        for (int j = 0; j < 2; ++j) {
            const int nt = wid * 2 + j;
            short8 bv = *(const short8*)(bbase + (size_t)nt * 16 * D_FEAT);
            acc[j] = __builtin_amdgcn_mfma_f32_16x16x32_bf16(av, bv, acc[j], 0, 0, 0);
        }
    }

    // C-write (round-2-verified mapping): row = rbase+r, col = nt*16 + cit
    const int rbase = (lane >> 4) * 4;
#pragma unroll
    for (int j = 0; j < 2; ++j) {
        const int col = (wid * 2 + j) * 16 + cit;
#pragma unroll
        for (int r = 0; r < 4; ++r) {
            out[(size_t)(n0 + rbase + r) * OUT_DIM + col] = acc[j][r];
        }
    }
}

extern "C" void kernel_launch(void* const* d_in, const int* in_sizes, int n_in,
                              void* d_out, int out_size, void* d_ws, size_t ws_size,
                              hipStream_t stream) {
    const float* x        = (const float*)d_in[0];
    const int*   edge_src = (const int*)d_in[1];
    const int*   edge_dst = (const int*)d_in[2];
    const float* edge_w   = (const float*)d_in[3];
    const float* W        = (const float*)d_in[4];
    float* out = (float*)d_out;

    char* ws = (char*)d_ws;
    unsigned int*   xq     = (unsigned int*)(ws);                // 5,120,000 B (int8 table)
    float*          scl    = (float*)(ws + 5120000);             //    80,000 B
    unsigned short* wt     = (unsigned short*)(ws + 5200000);    //   393,216 B
    int*            cursor = (int*)(ws + 5593216);               //   240,000 B
    unsigned int*   epack  = (unsigned int*)(ws + 5833216);      // 15,360,000 B
    // total: 21,193,216 B

    hipMemsetAsync(cursor, 0, 240000, stream);

    prep<<<NB_X + NB_W + NB_F, 256, 0, stream>>>(x, W, edge_src, edge_dst, edge_w,
                                                 xq, scl, wt, cursor, epack);

    fused_gather_gemm<<<N_NODES / TILE, 512, 0, stream>>>((const unsigned char*)xq, scl, wt,
                                                          cursor, epack, out);
}

// Round 15
// 174.661 us; speedup vs baseline: 1.0219x; 1.0219x over previous
//
#include <hip/hip_runtime.h>

#define N_NODES 20000
#define D_FEAT 256
#define N_SUPPORT 3
#define N_EDGES 320000
#define OUT_DIM 256
#define TOTAL_E (N_SUPPORT * N_EDGES)
#define CAP 64                      // per-(s,dst) bucket; mean 16, P(>64) ~ 1e-9
#define KDIM (N_SUPPORT * D_FEAT)   // 768
#define NBUCKET (N_SUPPORT * N_NODES)

typedef __attribute__((ext_vector_type(8))) short short8;
typedef __attribute__((ext_vector_type(8))) unsigned short ushort8;
typedef __attribute__((ext_vector_type(4))) float f32x4;

__device__ inline unsigned short f2bf(float f) {
    unsigned int u = __float_as_uint(f);
    u += 0x7fff + ((u >> 16) & 1);  // round-to-nearest-even
    return (unsigned short)(u >> 16);
}

// ---------------- prep1: quantize_x | convert_w (producers) ----------------
#define NB_X (N_NODES / 4)          // 5000 blocks, 4 waves/block, 1 row/wave
#define NB_W (N_SUPPORT * D_FEAT)   // 768
#define NB_F (TOTAL_E / 256)        // 3750

__global__ void __launch_bounds__(256) prep1(const float* __restrict__ x, const float* __restrict__ W,
        unsigned int* __restrict__ xq, float* __restrict__ scl, unsigned short* __restrict__ wt) {
    const int bid = blockIdx.x;
    const int tid = threadIdx.x;
    if (bid < NB_X) {
        // per-row int8 quantization: row = bid*4 + wid, lane owns 4 cols
        const int row = bid * 4 + (tid >> 6);
        const int lane = tid & 63;
        float4 v = ((const float4*)x)[row * 64 + lane];
        float m = fmaxf(fmaxf(fabsf(v.x), fabsf(v.y)), fmaxf(fabsf(v.z), fabsf(v.w)));
#pragma unroll
        for (int d = 1; d < 64; d <<= 1) m = fmaxf(m, __shfl_xor(m, d, 64));
        const float inv = (m > 0.f) ? 127.0f / m : 0.f;
        int q0 = (int)rintf(v.x * inv) + 128;
        int q1 = (int)rintf(v.y * inv) + 128;
        int q2 = (int)rintf(v.z * inv) + 128;
        int q3 = (int)rintf(v.w * inv) + 128;
        unsigned int pk = (unsigned int)q0 | ((unsigned int)q1 << 8)
                        | ((unsigned int)q2 << 16) | ((unsigned int)q3 << 24);
        xq[row * 64 + lane] = pk;
        if (lane == 0) scl[row] = m * (1.0f / 127.0f);
    } else {
        const int row = bid - NB_X;        // s*256 + k
        const int s = row >> 8, k = row & 255;
        wt[((size_t)s * OUT_DIM + tid) * D_FEAT + k] = f2bf(W[(size_t)row * OUT_DIM + tid]);
    }
}

// ---------------- prep2: fill_edges (consumer of scl, separate launch) ----------------
__global__ void __launch_bounds__(256) prep2(const int* __restrict__ src, const int* __restrict__ dst,
        const float* __restrict__ w, const float* __restrict__ scl,
        int* __restrict__ cursor, unsigned int* __restrict__ epack) {
    const int i = blockIdx.x * 256 + threadIdx.x;
    if (i >= TOTAL_E) return;
    const int s = i / N_EDGES;
    const int sv = src[i];
    const int b = s * N_NODES + dst[i];
    const int pos = atomicAdd(&cursor[b], 1);
    if (pos < CAP) {
        const float wq = w[i] * scl[sv];   // fold dequant scale into edge weight
        epack[(size_t)b * CAP + pos] = (unsigned int)sv | (((unsigned int)f2bf(wq)) << 16);
    }
}

// ---------------- aggregate: one 32-lane half per (s,node) bucket -> hb row slice ----------------
// 256 threads = 8 halves/block; grid 7500 (29.3 blocks/CU vs residency 8 -> ~2% tail).
// No LDS, no barrier. Inner loop = r13-verified ILP-4 int8 body.
__global__ void __launch_bounds__(256) aggregate(
        const unsigned char* __restrict__ xq, const int* __restrict__ cursor,
        const unsigned int* __restrict__ epack, unsigned short* __restrict__ hb) {
    const int b = blockIdx.x * 8 + (threadIdx.x >> 5);   // bucket id = s*N_NODES + node
    const int l32 = threadIdx.x & 31;
    const int xoff = l32 * 8;                  // 8 cols x 1 B
    const int s = b / N_NODES;
    const int node = b - s * N_NODES;

    int cnt = cursor[b]; if (cnt > CAP) cnt = CAP;
    const unsigned int* ep = epack + (size_t)b * CAP;

    float a[8];
#pragma unroll
    for (int j = 0; j < 8; ++j) a[j] = 0.f;
    float sw = 0.f;

    int it = 0;
    for (; it + 3 < cnt; it += 4) {        // 4 independent 8B table loads in flight
        const uint4 pk = *(const uint4*)(ep + it);
        const uint2 u0 = *(const uint2*)(xq + ((size_t)(pk.x & 0xFFFFu) << 8) + xoff);
        const uint2 u1 = *(const uint2*)(xq + ((size_t)(pk.y & 0xFFFFu) << 8) + xoff);
        const uint2 u2 = *(const uint2*)(xq + ((size_t)(pk.z & 0xFFFFu) << 8) + xoff);
        const uint2 u3 = *(const uint2*)(xq + ((size_t)(pk.w & 0xFFFFu) << 8) + xoff);
        const float w0 = __uint_as_float(pk.x & 0xFFFF0000u);
        const float w1 = __uint_as_float(pk.y & 0xFFFF0000u);
        const float w2 = __uint_as_float(pk.z & 0xFFFF0000u);
        const float w3 = __uint_as_float(pk.w & 0xFFFF0000u);
        sw += w0 + w1 + w2 + w3;
#pragma unroll
        for (int j = 0; j < 4; ++j) {
            const int sh = 8 * j;
            a[j]     += w0 * (float)((u0.x >> sh) & 0xffu) + w1 * (float)((u1.x >> sh) & 0xffu)
                      + w2 * (float)((u2.x >> sh) & 0xffu) + w3 * (float)((u3.x >> sh) & 0xffu);
            a[4 + j] += w0 * (float)((u0.y >> sh) & 0xffu) + w1 * (float)((u1.y >> sh) & 0xffu)
                      + w2 * (float)((u2.y >> sh) & 0xffu) + w3 * (float)((u3.y >> sh) & 0xffu);
        }
    }
    for (; it < cnt; ++it) {               // <=3 cleanup iterations
        const unsigned int pe = ep[it];
        const uint2 u = *(const uint2*)(xq + ((size_t)(pe & 0xFFFFu) << 8) + xoff);
        const float wv = __uint_as_float(pe & 0xFFFF0000u);
        sw += wv;
#pragma unroll
        for (int j = 0; j < 4; ++j) {
            const int sh = 8 * j;
            a[j]     += wv * (float)((u.x >> sh) & 0xffu);
            a[4 + j] += wv * (float)((u.y >> sh) & 0xffu);
        }
    }

    ushort8 o;
    const float bias = 128.f * sw;
#pragma unroll
    for (int j = 0; j < 8; ++j) o[j] = f2bf(a[j] - bias);
    *(ushort8*)(hb + (size_t)node * KDIM + s * D_FEAT + xoff) = o;
}

// ---------------- gemm_h: out[16 rows][256] = hb @ W via MFMA ----------------
// 256 threads = 4 waves; wave -> 4 n-tiles x 24 k-steps. A from global hb.
// Grid 1250 < residency capacity -> single cohort, no tail.
__global__ void __launch_bounds__(256) gemm_h(
        const unsigned short* __restrict__ hb, const unsigned short* __restrict__ wt,
        float* __restrict__ out) {
    const int n0 = blockIdx.x * 16;
    const int wid = threadIdx.x >> 6;
    const int lane = threadIdx.x & 63;
    const int cit = lane & 15;
    const int kgrp = (lane >> 4) * 8;

    const short* arow = (const short*)hb + (size_t)(n0 + cit) * KDIM + kgrp;

    f32x4 acc[4];
#pragma unroll
    for (int j = 0; j < 4; ++j) acc[j] = (f32x4){0.f, 0.f, 0.f, 0.f};

#pragma unroll
    for (int kk = 0; kk < KDIM / 32; ++kk) {   // 24 k-steps
        const int k0 = kk * 32;
        short8 av = *(const short8*)(arow + k0);
        const int s = k0 >> 8;
        const int kp = (k0 & 255) + kgrp;
        const short* bbase = (const short*)wt + (size_t)s * D_FEAT * OUT_DIM
                           + (size_t)cit * D_FEAT + kp;
#pragma unroll
        for (int j = 0; j < 4; ++j) {
            const int nt = wid * 4 + j;
            short8 bv = *(const short8*)(bbase + (size_t)nt * 16 * D_FEAT);
            acc[j] = __builtin_amdgcn_mfma_f32_16x16x32_bf16(av, bv, acc[j], 0, 0, 0);
        }
    }

    // C-write (round-2-verified mapping): row = rbase+r, col = nt*16 + cit
    const int rbase = (lane >> 4) * 4;
#pragma unroll
    for (int j = 0; j < 4; ++j) {
        const int col = (wid * 4 + j) * 16 + cit;
#pragma unroll
        for (int r = 0; r < 4; ++r) {
            out[(size_t)(n0 + rbase + r) * OUT_DIM + col] = acc[j][r];
        }
    }
}

extern "C" void kernel_launch(void* const* d_in, const int* in_sizes, int n_in,
                              void* d_out, int out_size, void* d_ws, size_t ws_size,
                              hipStream_t stream) {
    const float* x        = (const float*)d_in[0];
    const int*   edge_src = (const int*)d_in[1];
    const int*   edge_dst = (const int*)d_in[2];
    const float* edge_w   = (const float*)d_in[3];
    const float* W        = (const float*)d_in[4];
    float* out = (float*)d_out;

    char* ws = (char*)d_ws;
    unsigned int*   xq     = (unsigned int*)(ws);                //  5,120,000 B (int8 table)
    float*          scl    = (float*)(ws + 5120000);             //     80,000 B
    unsigned short* wt     = (unsigned short*)(ws + 5200000);    //    393,216 B
    int*            cursor = (int*)(ws + 5593216);               //    240,000 B
    unsigned int*   epack  = (unsigned int*)(ws + 5833216);      // 15,360,000 B
    unsigned short* hb     = (unsigned short*)(ws + 21193216);   // 30,720,000 B
    // total: 51,913,216 B

    hipMemsetAsync(cursor, 0, 240000, stream);

    prep1<<<NB_X + NB_W, 256, 0, stream>>>(x, W, xq, scl, wt);
    prep2<<<NB_F, 256, 0, stream>>>(edge_src, edge_dst, edge_w, scl, cursor, epack);

    aggregate<<<NBUCKET / 8, 256, 0, stream>>>((const unsigned char*)xq, cursor, epack, hb);

    gemm_h<<<N_NODES / 16, 256, 0, stream>>>(hb, wt, out);
}

// Round 16
// 132.401 us; speedup vs baseline: 1.3480x; 1.3192x over previous
//
#include <hip/hip_runtime.h>

#define N_NODES 20000
#define D_FEAT 256
#define N_SUPPORT 3
#define N_EDGES 320000
#define OUT_DIM 256
#define TOTAL_E (N_SUPPORT * N_EDGES)
#define CAP 64                      // per-(s,dst) bucket; mean 16, P(>64) ~ 1e-9
#define KDIM (N_SUPPORT * D_FEAT)   // 768
#define NBUCKET (N_SUPPORT * N_NODES)
#define GM_ROWS 128
#define GM_BLOCKS ((N_NODES + GM_ROWS - 1) / GM_ROWS)   // 157

typedef __attribute__((ext_vector_type(8))) short short8;
typedef __attribute__((ext_vector_type(8))) unsigned short ushort8;
typedef __attribute__((ext_vector_type(4))) float f32x4;

__device__ inline unsigned short f2bf(float f) {
    unsigned int u = __float_as_uint(f);
    u += 0x7fff + ((u >> 16) & 1);  // round-to-nearest-even
    return (unsigned short)(u >> 16);
}

// ---------------- prep1: quantize_x | convert_w (producers) ----------------
#define NB_X (N_NODES / 4)          // 5000 blocks, 4 waves/block, 1 row/wave
#define NB_W (N_SUPPORT * D_FEAT)   // 768
#define NB_F (TOTAL_E / 256)        // 3750

__global__ void __launch_bounds__(256) prep1(const float* __restrict__ x, const float* __restrict__ W,
        unsigned int* __restrict__ xq, float* __restrict__ scl, unsigned short* __restrict__ wt) {
    const int bid = blockIdx.x;
    const int tid = threadIdx.x;
    if (bid < NB_X) {
        // per-row int8 quantization: row = bid*4 + wid, lane owns 4 cols
        const int row = bid * 4 + (tid >> 6);
        const int lane = tid & 63;
        float4 v = ((const float4*)x)[row * 64 + lane];
        float m = fmaxf(fmaxf(fabsf(v.x), fabsf(v.y)), fmaxf(fabsf(v.z), fabsf(v.w)));
#pragma unroll
        for (int d = 1; d < 64; d <<= 1) m = fmaxf(m, __shfl_xor(m, d, 64));
        const float inv = (m > 0.f) ? 127.0f / m : 0.f;
        int q0 = (int)rintf(v.x * inv) + 128;
        int q1 = (int)rintf(v.y * inv) + 128;
        int q2 = (int)rintf(v.z * inv) + 128;
        int q3 = (int)rintf(v.w * inv) + 128;
        unsigned int pk = (unsigned int)q0 | ((unsigned int)q1 << 8)
                        | ((unsigned int)q2 << 16) | ((unsigned int)q3 << 24);
        xq[row * 64 + lane] = pk;
        if (lane == 0) scl[row] = m * (1.0f / 127.0f);
    } else {
        const int row = bid - NB_X;        // s*256 + k
        const int s = row >> 8, k = row & 255;
        wt[((size_t)s * OUT_DIM + tid) * D_FEAT + k] = f2bf(W[(size_t)row * OUT_DIM + tid]);
    }
}

// ---------------- prep2: fill_edges (consumer of scl, separate launch) ----------------
__global__ void __launch_bounds__(256) prep2(const int* __restrict__ src, const int* __restrict__ dst,
        const float* __restrict__ w, const float* __restrict__ scl,
        int* __restrict__ cursor, unsigned int* __restrict__ epack) {
    const int i = blockIdx.x * 256 + threadIdx.x;
    if (i >= TOTAL_E) return;
    const int s = i / N_EDGES;
    const int sv = src[i];
    const int b = s * N_NODES + dst[i];
    const int pos = atomicAdd(&cursor[b], 1);
    if (pos < CAP) {
        const float wq = w[i] * scl[sv];   // fold dequant scale into edge weight
        epack[(size_t)b * CAP + pos] = (unsigned int)sv | (((unsigned int)f2bf(wq)) << 16);
    }
}

// ---------------- aggregate: one 32-lane half per (s,node) bucket -> hb row slice ----------------
__global__ void __launch_bounds__(256) aggregate(
        const unsigned char* __restrict__ xq, const int* __restrict__ cursor,
        const unsigned int* __restrict__ epack, unsigned short* __restrict__ hb) {
    const int b = blockIdx.x * 8 + (threadIdx.x >> 5);   // bucket id = s*N_NODES + node
    const int l32 = threadIdx.x & 31;
    const int xoff = l32 * 8;                  // 8 cols x 1 B
    const int s = b / N_NODES;
    const int node = b - s * N_NODES;

    int cnt = cursor[b]; if (cnt > CAP) cnt = CAP;
    const unsigned int* ep = epack + (size_t)b * CAP;

    float a[8];
#pragma unroll
    for (int j = 0; j < 8; ++j) a[j] = 0.f;
    float sw = 0.f;

    int it = 0;
    for (; it + 3 < cnt; it += 4) {        // 4 independent 8B table loads in flight
        const uint4 pk = *(const uint4*)(ep + it);
        const uint2 u0 = *(const uint2*)(xq + ((size_t)(pk.x & 0xFFFFu) << 8) + xoff);
        const uint2 u1 = *(const uint2*)(xq + ((size_t)(pk.y & 0xFFFFu) << 8) + xoff);
        const uint2 u2 = *(const uint2*)(xq + ((size_t)(pk.z & 0xFFFFu) << 8) + xoff);
        const uint2 u3 = *(const uint2*)(xq + ((size_t)(pk.w & 0xFFFFu) << 8) + xoff);
        const float w0 = __uint_as_float(pk.x & 0xFFFF0000u);
        const float w1 = __uint_as_float(pk.y & 0xFFFF0000u);
        const float w2 = __uint_as_float(pk.z & 0xFFFF0000u);
        const float w3 = __uint_as_float(pk.w & 0xFFFF0000u);
        sw += w0 + w1 + w2 + w3;
#pragma unroll
        for (int j = 0; j < 4; ++j) {
            const int sh = 8 * j;
            a[j]     += w0 * (float)((u0.x >> sh) & 0xffu) + w1 * (float)((u1.x >> sh) & 0xffu)
                      + w2 * (float)((u2.x >> sh) & 0xffu) + w3 * (float)((u3.x >> sh) & 0xffu);
            a[4 + j] += w0 * (float)((u0.y >> sh) & 0xffu) + w1 * (float)((u1.y >> sh) & 0xffu)
                      + w2 * (float)((u2.y >> sh) & 0xffu) + w3 * (float)((u3.y >> sh) & 0xffu);
        }
    }
    for (; it < cnt; ++it) {               // <=3 cleanup iterations
        const unsigned int pe = ep[it];
        const uint2 u = *(const uint2*)(xq + ((size_t)(pe & 0xFFFFu) << 8) + xoff);
        const float wv = __uint_as_float(pe & 0xFFFF0000u);
        sw += wv;
#pragma unroll
        for (int j = 0; j < 4; ++j) {
            const int sh = 8 * j;
            a[j]     += wv * (float)((u.x >> sh) & 0xffu);
            a[4 + j] += wv * (float)((u.y >> sh) & 0xffu);
        }
    }

    ushort8 o;
    const float bias = 128.f * sw;
#pragma unroll
    for (int j = 0; j < 8; ++j) o[j] = f2bf(a[j] - bias);
    *(ushort8*)(hb + (size_t)node * KDIM + s * D_FEAT + xoff) = o;
}

// ---------------- gemm_h: BM=128 tile, LDS-staged B, 512 thr / 8 waves ----------------
// Block: rows n0..n0+127 (8 M-tiles, one per wave) x 256 cols (16 n-tiles per wave).
// Loop 6 k-chunks of 128: stage B chunk [256 n][128 k] in LDS (pad +8 -> 2-way banks),
// A-fragments direct from global hb (distinct rows per wave -> no duplication).
__global__ void __launch_bounds__(512) gemm_h(
        const unsigned short* __restrict__ hb, const unsigned short* __restrict__ wt,
        float* __restrict__ out) {
    __shared__ unsigned short bs[OUT_DIM][136];   // 256 x 136 x 2B = 69,632 B
    const int n0 = blockIdx.x * GM_ROWS;
    const int wid = threadIdx.x >> 6;
    const int lane = threadIdx.x & 63;
    const int cit = lane & 15;
    const int kgrp = (lane >> 4) * 8;
    const bool valid = (n0 + wid * 16) < N_NODES;
    const int arow_idx = valid ? (n0 + wid * 16 + cit) : 0;
    const short* arow = (const short*)hb + (size_t)arow_idx * KDIM + kgrp;

    f32x4 acc[16];
#pragma unroll
    for (int j = 0; j < 16; ++j) acc[j] = (f32x4){0.f, 0.f, 0.f, 0.f};

    for (int kc = 0; kc < 6; ++kc) {       // k-chunks of 128
        const int s = kc >> 1;
        const int kb = (kc & 1) * 128;
        if (kc) __syncthreads();           // protect previous chunk's reads
        // stage B chunk: 256 n x 16 groups of 8 shorts = 4096 iterations
        for (int i = threadIdx.x; i < 4096; i += 512) {
            const int n = i >> 4;
            const int k8 = (i & 15) << 3;
            *(ushort8*)&bs[n][k8] =
                *(const ushort8*)(wt + ((size_t)s * OUT_DIM + n) * D_FEAT + kb + k8);
        }
        __syncthreads();

#pragma unroll
        for (int ks = 0; ks < 4; ++ks) {   // 4 k-steps of 32 within the chunk
            short8 av = *(const short8*)(arow + kc * 128 + ks * 32);
#pragma unroll
            for (int nt = 0; nt < 16; ++nt) {
                short8 bv = *(const short8*)&bs[nt * 16 + cit][ks * 32 + kgrp];
                acc[nt] = __builtin_amdgcn_mfma_f32_16x16x32_bf16(av, bv, acc[nt], 0, 0, 0);
            }
        }
    }

    // C-write (round-2-verified mapping): row = rbase+r, col = nt*16 + cit
    if (valid) {
        const int rbase = (lane >> 4) * 4;
#pragma unroll
        for (int nt = 0; nt < 16; ++nt) {
            const int col = nt * 16 + cit;
#pragma unroll
            for (int r = 0; r < 4; ++r) {
                out[(size_t)(n0 + wid * 16 + rbase + r) * OUT_DIM + col] = acc[nt][r];
            }
        }
    }
}

extern "C" void kernel_launch(void* const* d_in, const int* in_sizes, int n_in,
                              void* d_out, int out_size, void* d_ws, size_t ws_size,
                              hipStream_t stream) {
    const float* x        = (const float*)d_in[0];
    const int*   edge_src = (const int*)d_in[1];
    const int*   edge_dst = (const int*)d_in[2];
    const float* edge_w   = (const float*)d_in[3];
    const float* W        = (const float*)d_in[4];
    float* out = (float*)d_out;

    char* ws = (char*)d_ws;
    unsigned int*   xq     = (unsigned int*)(ws);                //  5,120,000 B (int8 table)
    float*          scl    = (float*)(ws + 5120000);             //     80,000 B
    unsigned short* wt     = (unsigned short*)(ws + 5200000);    //    393,216 B
    int*            cursor = (int*)(ws + 5593216);               //    240,000 B
    unsigned int*   epack  = (unsigned int*)(ws + 5833216);      // 15,360,000 B
    unsigned short* hb     = (unsigned short*)(ws + 21193216);   // 30,720,000 B
    // total: 51,913,216 B

    hipMemsetAsync(cursor, 0, 240000, stream);

    prep1<<<NB_X + NB_W, 256, 0, stream>>>(x, W, xq, scl, wt);
    prep2<<<NB_F, 256, 0, stream>>>(edge_src, edge_dst, edge_w, scl, cursor, epack);

    aggregate<<<NBUCKET / 8, 256, 0, stream>>>((const unsigned char*)xq, cursor, epack, hb);

    gemm_h<<<GM_BLOCKS, 512, 0, stream>>>(hb, wt, out);
}